// Round 11
// baseline (179.407 us; speedup 1.0000x reference)
//
#include <hip/hip_runtime.h>
#include <hip/hip_bf16.h>

// SO3Conv restructured:
//   PT_l[(yo,v)][(x,u)] = psi_l scaled, bf16   (psi = D.w/sqrt(512))
//   A_l[(b,i)][(x,u)]   = permuted x, bf16
//   Y_l[(b,i)][(yo,v)]  = A_l . PT_l^T  via mfma_f32_16x16x32_bf16
// l=0..5, d=2l+1, off_l = {0,1,10,35,84,165}.
// main_gemm: persistent queue over 1144 128x128 tiles, template-d bodies,
// LDS-staged COALESCED epilogue (per (b,yo): d^2 contiguous out floats).

#define NT 256
#define NTILES 1144
#define NWORKERS 768
typedef __bf16 bf16x8 __attribute__((ext_vector_type(8)));
typedef float f32x4 __attribute__((ext_vector_type(4)));
typedef unsigned int u32;

__device__ __forceinline__ void gload_lds16(const void* g, void* l) {
  __builtin_amdgcn_global_load_lds(
      (const __attribute__((address_space(1))) u32*)g,
      (__attribute__((address_space(3))) u32*)l, 16, 0, 0);
}

__device__ __forceinline__ void decode_s(int s, int& off, int& d) {
  if (s >= 165)      { off = 165; d = 11; }
  else if (s >= 84)  { off = 84;  d = 9; }
  else if (s >= 35)  { off = 35;  d = 7; }
  else if (s >= 10)  { off = 10;  d = 5; }
  else if (s >= 1)   { off = 1;   d = 3; }
  else               { off = 0;   d = 1; }
}

// ---------------------------------------------------------------------------
// Kernel 0: prep_all (7936 blocks).
//   [0,4096):    wb = bf16(w), 8 elems/thread; bx0 also zeroes queue counter.
//   [4096,4864): DT[s][g] = bf16(D[g][s]), padded to 384 rows.
//   [4864,7936): build_A — per (b,l) LDS transpose, compile-time D/OFF.
// ---------------------------------------------------------------------------
template<int D, int OFF>
__device__ __forceinline__ void build_one(const float* __restrict__ X,
                                          __hip_bfloat16* __restrict__ A,
                                          int b, __hip_bfloat16* sm) {
  const float* src = X + (size_t)b * (128 * 286) + OFF;
  for (int e = threadIdx.x; e < 128 * D * D; e += NT) {
    const int x = e / (D * D), r = e - x * (D * D);
    sm[e] = __float2bfloat16(src[x * 286 + r]);
  }
  __syncthreads();
  __hip_bfloat16* dst = A + (size_t)65536 * OFF + (size_t)b * (D * 128 * D);
  for (int o = threadIdx.x; o < D * 128 * D; o += NT) {
    const int i = o / (128 * D);
    const int rem = o - i * (128 * D);
    const int x = rem / D, u = rem - x * D;
    dst[o] = sm[x * D * D + u * D + i];
  }
}

__global__ __launch_bounds__(NT)
void prep_all(const float* __restrict__ w, const float* __restrict__ Dm,
              const float* __restrict__ X,
              __hip_bfloat16* __restrict__ wb, __hip_bfloat16* __restrict__ DT,
              __hip_bfloat16* __restrict__ A, int* __restrict__ cnt) {
  __shared__ __hip_bfloat16 sm[128 * 121];
  const int bx = blockIdx.x;
  if (bx == 0 && threadIdx.x == 0) *cnt = 0;
  if (bx < 4096) {
    const int t = bx * NT + threadIdx.x;
    const float4 a = reinterpret_cast<const float4*>(w)[t * 2];
    const float4 b = reinterpret_cast<const float4*>(w)[t * 2 + 1];
    __hip_bfloat16 v[8];
    v[0] = __float2bfloat16(a.x); v[1] = __float2bfloat16(a.y);
    v[2] = __float2bfloat16(a.z); v[3] = __float2bfloat16(a.w);
    v[4] = __float2bfloat16(b.x); v[5] = __float2bfloat16(b.y);
    v[6] = __float2bfloat16(b.z); v[7] = __float2bfloat16(b.w);
    *reinterpret_cast<bf16x8*>(&wb[t * 8]) = *reinterpret_cast<bf16x8*>(v);
  } else if (bx < 4864) {
    const int e = (bx - 4096) * NT + threadIdx.x;  // 196,608 = 384*512
    const int s = e >> 9, g = e & 511;
    DT[e] = (s < 286) ? __float2bfloat16(Dm[g * 286 + s]) : __float2bfloat16(0.0f);
  } else {
    const int b2 = bx - 4864;
    if (b2 < 512)       build_one<11, 165>(X, A, b2, sm);
    else if (b2 < 1024) build_one<9, 84>(X, A, b2 - 512, sm);
    else if (b2 < 1536) build_one<7, 35>(X, A, b2 - 1024, sm);
    else if (b2 < 2048) build_one<5, 10>(X, A, b2 - 1536, sm);
    else if (b2 < 2560) build_one<3, 1>(X, A, b2 - 2048, sm);
    else                build_one<1, 0>(X, A, b2 - 2560, sm);
  }
}

// ---------------------------------------------------------------------------
// Kernel 1: psi MFMA GEMM (double-buffered; unchanged, proven).
// ---------------------------------------------------------------------------
__device__ __forceinline__ void stage_tile(
    const __hip_bfloat16* __restrict__ Ap, const __hip_bfloat16* __restrict__ Bp,
    int LDK, int ktv, int m0, int n0, int tid, int wave,
    __hip_bfloat16* sA, __hip_bfloat16* sB) {
#pragma unroll
  for (int c = 0; c < 4; ++c) {
    const int q = c * 256 + tid;
    const int row = q >> 3, slot = q & 7;
    const int scol = ((slot ^ (row & 7)) << 3);
    gload_lds16(&Ap[(m0 + row) * LDK + ktv + scol], &sA[(c * 256 + wave * 64) << 3]);
    gload_lds16(&Bp[(n0 + row) * LDK + ktv + scol], &sB[(c * 256 + wave * 64) << 3]);
  }
}

__device__ __forceinline__ void load_frags(
    const __hip_bfloat16* sA, const __hip_bfloat16* sB,
    int wr, int wc, int r15, int khi, bf16x8 (&af)[4][2], bf16x8 (&bf)[4][2]) {
#pragma unroll
  for (int m = 0; m < 4; ++m)
#pragma unroll
    for (int kk = 0; kk < 2; ++kk) {
      const int row = wr * 64 + m * 16 + r15;
      const int slot = (kk * 4 + khi) ^ (row & 7);
      af[m][kk] = *reinterpret_cast<const bf16x8*>(&sA[row * 64 + slot * 8]);
    }
#pragma unroll
  for (int n = 0; n < 4; ++n)
#pragma unroll
    for (int kk = 0; kk < 2; ++kk) {
      const int row = wc * 64 + n * 16 + r15;
      const int slot = (kk * 4 + khi) ^ (row & 7);
      bf[n][kk] = *reinterpret_cast<const bf16x8*>(&sB[row * 64 + slot * 8]);
    }
}

__device__ __forceinline__ void do_mfma(
    const bf16x8 (&af)[4][2], const bf16x8 (&bf)[4][2], f32x4 (&acc)[4][4]) {
#pragma unroll
  for (int kk = 0; kk < 2; ++kk)
#pragma unroll
    for (int m = 0; m < 4; ++m)
#pragma unroll
      for (int n = 0; n < 4; ++n)
        acc[m][n] = __builtin_amdgcn_mfma_f32_16x16x32_bf16(
            af[m][kk], bf[n][kk], acc[m][n], 0, 0, 0);
}

__global__ __launch_bounds__(NT)
void psi_mfma(const __hip_bfloat16* __restrict__ wb,
              const __hip_bfloat16* __restrict__ DT,
              __hip_bfloat16* __restrict__ PT) {
  const int m0 = blockIdx.x * 128, n0 = blockIdx.y * 128;

  __shared__ __hip_bfloat16 sA[2][128 * 64];
  __shared__ __hip_bfloat16 sB[2][128 * 64];

  const int tid = threadIdx.x;
  const int lane = tid & 63, wave = tid >> 6;
  const int wr = wave & 1, wc = wave >> 1;
  const int r15 = lane & 15, khi = lane >> 4;

  f32x4 acc[4][4] = {};
  bf16x8 af[4][2], bf[4][2];

  stage_tile(wb, DT, 512, 0, m0, n0, tid, wave, sA[0], sB[0]);
  __syncthreads();
  int cur = 0;
  for (int t = 0; t < 8; ++t) {
    if (t + 1 < 8)
      stage_tile(wb, DT, 512, (t + 1) << 6, m0, n0, tid, wave, sA[cur ^ 1], sB[cur ^ 1]);
    load_frags(sA[cur], sB[cur], wr, wc, r15, khi, af, bf);
    do_mfma(af, bf, acc);
    if (t + 1 < 8) { __syncthreads(); cur ^= 1; }
  }

#pragma unroll
  for (int n = 0; n < 4; ++n) {
    const int s = n0 + wc * 64 + n * 16 + r15;
    if (s >= 286) continue;
    int off, d;
    decode_s(s, off, d);
    const int rel = s - off;
    const int u = rel / d, v = rel - u * d;
    const float scale = 1.0f / (256.0f * sqrtf((float)d));
    __hip_bfloat16* Pl = PT + off * 16384;
    const int Kd = 128 * d;
#pragma unroll
    for (int m = 0; m < 4; ++m)
#pragma unroll
      for (int j = 0; j < 4; ++j) {
        const int row = m0 + wr * 64 + m * 16 + khi * 4 + j;
        const int x = row >> 7, y = row & 127;
        Pl[(y * d + v) * Kd + (x * d + u)] = __float2bfloat16(acc[m][n][j] * scale);
      }
  }
}

// ---------------------------------------------------------------------------
// Kernel 2: persistent main GEMM, template-D tile bodies.
// K-loop identical to R9 (single 32 KiB buffer, XOR swizzle, gload_lds).
// Epilogue: acc -> LDS f32 chunk [64][129] (aliases staging) -> coalesced
// out stores: per (b,yo) the d^2 outputs off+v*d+i are CONTIGUOUS.
// ---------------------------------------------------------------------------
template<int D, int OFF>
__device__ __forceinline__ void tile_body(
    const __hip_bfloat16* __restrict__ Aall,
    const __hip_bfloat16* __restrict__ PTall,
    float* __restrict__ out, int bx,
    __hip_bfloat16* sA, __hip_bfloat16* sB, float* sE) {
  const int tid = threadIdx.x;
  const int lane = tid & 63, wave = tid >> 6;
  const int wr = wave & 1, wc = wave >> 1;
  const int r15 = lane & 15, khi = lane >> 4;

  constexpr int Kn = 128 * D;
  constexpr int nk = 2 * D;
  const int bm = bx % (4 * D);       // bm fastest: consecutive claims share B
  const int bn = bx / (4 * D);
  const __hip_bfloat16* A  = Aall  + 65536 * OFF;
  const __hip_bfloat16* BT = PTall + 16384 * OFF;
  const int m0 = bm * 128, n0 = bn * 128;

  f32x4 acc[4][4] = {};
  bf16x8 af[4][2], bf[4][2];

  for (int t = 0; t < nk; ++t) {
    const int kt = t << 6;
#pragma unroll
    for (int c = 0; c < 4; ++c) {
      const int q = c * 256 + tid;
      const int row = q >> 3, slot = q & 7;
      const int scol = ((slot ^ (row & 7)) << 3);
      gload_lds16(&A[(m0 + row) * Kn + kt + scol], &sA[(c * 256 + wave * 64) << 3]);
      gload_lds16(&BT[(n0 + row) * Kn + kt + scol], &sB[(c * 256 + wave * 64) << 3]);
    }
    __syncthreads();
    load_frags(sA, sB, wr, wc, r15, khi, af, bf);
    do_mfma(af, bf, acc);
    __syncthreads();   // last iter: guards epilogue aliasing of sA/sB
  }

  // Coalesced epilogue, two 64-row chunks (chunk ch holds wr==ch rows).
#pragma unroll
  for (int ch = 0; ch < 2; ++ch) {
    if (wr == ch) {
#pragma unroll
      for (int m = 0; m < 4; ++m)
#pragma unroll
        for (int j = 0; j < 4; ++j) {
          const int lr = m * 16 + khi * 4 + j;          // 0..63
#pragma unroll
          for (int n = 0; n < 4; ++n) {
            const int c = wc * 64 + n * 16 + r15;       // 0..127
            sE[lr * 129 + c] = acc[m][n][j];
          }
        }
    }
    __syncthreads();
    const int base_row = m0 + ch * 64;
    const int b_lo = base_row / D;                       // compile-time D
    const int yo_lo = n0 / D;
    constexpr int NBMAX = 64 / D + 2;
    constexpr int NYOC = 128 / D + 2;
    constexpr int TOT = NBMAX * NYOC * D * D;
    for (int e = tid; e < TOT; e += NT) {
      const int s = e % (D * D);
      const int t2 = e / (D * D);
      const int yos = t2 % NYOC;
      const int bs = t2 / NYOC;
      const int b = b_lo + bs;
      const int yo = yo_lo + yos;
      const int i = s % D, v = s / D;                    // i fastest: contiguous
      const int row = b * D + i;
      const int col = yo * D + v;
      if (row < base_row || row >= base_row + 64) continue;
      if (col < n0 || col >= n0 + 128) continue;
      out[(size_t)b * 36608 + yo * 286 + OFF + v * D + i] =
          sE[(row - base_row) * 129 + (col - n0)];
    }
    __syncthreads();
  }
}

__global__ __launch_bounds__(NT)
void main_gemm(const __hip_bfloat16* __restrict__ Aall,
               const __hip_bfloat16* __restrict__ PTall,
               float* __restrict__ out, int* __restrict__ cnt) {
  __shared__ __align__(16) unsigned char smem[33024];   // staging 32K | epi 33K
  __shared__ int s_tile;
  __hip_bfloat16* sA = (__hip_bfloat16*)smem;
  __hip_bfloat16* sB = (__hip_bfloat16*)(smem + 16384);
  float* sE = (float*)smem;

  for (;;) {
    if (threadIdx.x == 0) s_tile = atomicAdd(cnt, 1);
    __syncthreads();               // broadcast tile id; guards LDS reuse
    const int bx = s_tile;
    if (bx >= NTILES) return;
    if (bx < 484)       tile_body<11, 165>(Aall, PTall, out, bx, sA, sB, sE);
    else if (bx < 808)  tile_body<9, 84>(Aall, PTall, out, bx - 484, sA, sB, sE);
    else if (bx < 1004) tile_body<7, 35>(Aall, PTall, out, bx - 808, sA, sB, sE);
    else if (bx < 1104) tile_body<5, 10>(Aall, PTall, out, bx - 1004, sA, sB, sE);
    else if (bx < 1140) tile_body<3, 1>(Aall, PTall, out, bx - 1104, sA, sB, sE);
    else                tile_body<1, 0>(Aall, PTall, out, bx - 1140, sA, sB, sE);
  }
}

// ---------------------------------------------------------------------------
extern "C" void kernel_launch(void* const* d_in, const int* in_sizes, int n_in,
                              void* d_out, int out_size, void* d_ws, size_t ws_size,
                              hipStream_t stream) {
  const float* x  = (const float*)d_in[0];  // (512,128,286)
  const float* w  = (const float*)d_in[1];  // (128,128,512)
  const float* Dm = (const float*)d_in[2];  // (512,286)
  float* out = (float*)d_out;               // (512,128,286)

  // Workspace (bf16 elems): PT 16384*286 ; A 65536*286 ; wb 16384*512 ;
  // DT 384*512 ; then a 4-byte work-queue counter.
  __hip_bfloat16* PT = (__hip_bfloat16*)d_ws;
  __hip_bfloat16* A  = PT + 16384 * 286;
  __hip_bfloat16* wb = A + 65536 * 286;
  __hip_bfloat16* DT = wb + 16384 * 512;
  int* cnt = (int*)(DT + 384 * 512);

  prep_all<<<dim3(7936), dim3(NT), 0, stream>>>(w, Dm, x, wb, DT, A, cnt);
  psi_mfma<<<dim3(128, 3), dim3(NT), 0, stream>>>(wb, DT, PT);
  main_gemm<<<dim3(NWORKERS), dim3(NT), 0, stream>>>(A, PT, out, cnt);
}

// Round 12
// 164.194 us; speedup vs baseline: 1.0927x; 1.0927x over previous
//
#include <hip/hip_runtime.h>
#include <hip/hip_bf16.h>

// SO3Conv restructured:
//   PT_l[(yo,v)][(x,u)] = psi_l scaled, bf16   (psi = D.w/sqrt(512))
//   A_l[(b,i)][(x,u)]   = permuted x, bf16
//   Y_l[(b,i)][(yo,v)]  = A_l . PT_l^T  via mfma_f32_16x16x32_bf16
// l=0..5, d=2l+1, off_l = {0,1,10,35,84,165}.
// main_gemm: grid of 1144 128x128 tiles (longest degree first), template-D
// bodies, ping-pong LDS + counted vmcnt(8) + RAW s_barrier (no drain),
// setprio(1) around MFMA cluster, direct-scatter epilogue (R9-proven).

#define NT 256
typedef __bf16 bf16x8 __attribute__((ext_vector_type(8)));
typedef float f32x4 __attribute__((ext_vector_type(4)));
typedef unsigned int u32;

__device__ __forceinline__ void gload_lds16(const void* g, void* l) {
  __builtin_amdgcn_global_load_lds(
      (const __attribute__((address_space(1))) u32*)g,
      (__attribute__((address_space(3))) u32*)l, 16, 0, 0);
}

__device__ __forceinline__ void decode_s(int s, int& off, int& d) {
  if (s >= 165)      { off = 165; d = 11; }
  else if (s >= 84)  { off = 84;  d = 9; }
  else if (s >= 35)  { off = 35;  d = 7; }
  else if (s >= 10)  { off = 10;  d = 5; }
  else if (s >= 1)   { off = 1;   d = 3; }
  else               { off = 0;   d = 1; }
}

// ---------------------------------------------------------------------------
// Kernel 0: prep_all (7936 blocks).
//   [0,4096):    wb = bf16(w), 8 elems/thread.
//   [4096,4864): DT[s][g] = bf16(D[g][s]), padded to 384 rows.
//   [4864,7936): build_A — per (b,l) LDS transpose, compile-time D/OFF.
// ---------------------------------------------------------------------------
template<int D, int OFF>
__device__ __forceinline__ void build_one(const float* __restrict__ X,
                                          __hip_bfloat16* __restrict__ A,
                                          int b, __hip_bfloat16* sm) {
  const float* src = X + (size_t)b * (128 * 286) + OFF;
  for (int e = threadIdx.x; e < 128 * D * D; e += NT) {
    const int x = e / (D * D), r = e - x * (D * D);
    sm[e] = __float2bfloat16(src[x * 286 + r]);
  }
  __syncthreads();
  __hip_bfloat16* dst = A + (size_t)65536 * OFF + (size_t)b * (D * 128 * D);
  for (int o = threadIdx.x; o < D * 128 * D; o += NT) {
    const int i = o / (128 * D);
    const int rem = o - i * (128 * D);
    const int x = rem / D, u = rem - x * D;
    dst[o] = sm[x * D * D + u * D + i];
  }
}

__global__ __launch_bounds__(NT)
void prep_all(const float* __restrict__ w, const float* __restrict__ Dm,
              const float* __restrict__ X,
              __hip_bfloat16* __restrict__ wb, __hip_bfloat16* __restrict__ DT,
              __hip_bfloat16* __restrict__ A) {
  __shared__ __hip_bfloat16 sm[128 * 121];
  const int bx = blockIdx.x;
  if (bx < 4096) {
    const int t = bx * NT + threadIdx.x;
    const float4 a = reinterpret_cast<const float4*>(w)[t * 2];
    const float4 b = reinterpret_cast<const float4*>(w)[t * 2 + 1];
    __hip_bfloat16 v[8];
    v[0] = __float2bfloat16(a.x); v[1] = __float2bfloat16(a.y);
    v[2] = __float2bfloat16(a.z); v[3] = __float2bfloat16(a.w);
    v[4] = __float2bfloat16(b.x); v[5] = __float2bfloat16(b.y);
    v[6] = __float2bfloat16(b.z); v[7] = __float2bfloat16(b.w);
    *reinterpret_cast<bf16x8*>(&wb[t * 8]) = *reinterpret_cast<bf16x8*>(v);
  } else if (bx < 4864) {
    const int e = (bx - 4096) * NT + threadIdx.x;  // 196,608 = 384*512
    const int s = e >> 9, g = e & 511;
    DT[e] = (s < 286) ? __float2bfloat16(Dm[g * 286 + s]) : __float2bfloat16(0.0f);
  } else {
    const int b2 = bx - 4864;
    if (b2 < 512)       build_one<11, 165>(X, A, b2, sm);
    else if (b2 < 1024) build_one<9, 84>(X, A, b2 - 512, sm);
    else if (b2 < 1536) build_one<7, 35>(X, A, b2 - 1024, sm);
    else if (b2 < 2048) build_one<5, 10>(X, A, b2 - 1536, sm);
    else if (b2 < 2560) build_one<3, 1>(X, A, b2 - 2048, sm);
    else                build_one<1, 0>(X, A, b2 - 2560, sm);
  }
}

// ---------------------------------------------------------------------------
// Shared helpers (proven R7 structure).
// ---------------------------------------------------------------------------
__device__ __forceinline__ void load_frags(
    const __hip_bfloat16* sA, const __hip_bfloat16* sB,
    int wr, int wc, int r15, int khi, bf16x8 (&af)[4][2], bf16x8 (&bf)[4][2]) {
#pragma unroll
  for (int m = 0; m < 4; ++m)
#pragma unroll
    for (int kk = 0; kk < 2; ++kk) {
      const int row = wr * 64 + m * 16 + r15;
      const int slot = (kk * 4 + khi) ^ (row & 7);
      af[m][kk] = *reinterpret_cast<const bf16x8*>(&sA[row * 64 + slot * 8]);
    }
#pragma unroll
  for (int n = 0; n < 4; ++n)
#pragma unroll
    for (int kk = 0; kk < 2; ++kk) {
      const int row = wc * 64 + n * 16 + r15;
      const int slot = (kk * 4 + khi) ^ (row & 7);
      bf[n][kk] = *reinterpret_cast<const bf16x8*>(&sB[row * 64 + slot * 8]);
    }
}

__device__ __forceinline__ void do_mfma(
    const bf16x8 (&af)[4][2], const bf16x8 (&bf)[4][2], f32x4 (&acc)[4][4]) {
#pragma unroll
  for (int kk = 0; kk < 2; ++kk)
#pragma unroll
    for (int m = 0; m < 4; ++m)
#pragma unroll
      for (int n = 0; n < 4; ++n)
        acc[m][n] = __builtin_amdgcn_mfma_f32_16x16x32_bf16(
            af[m][kk], bf[n][kk], acc[m][n], 0, 0, 0);
}

// ---------------------------------------------------------------------------
// Kernel 1: psi MFMA GEMM (double-buffered __syncthreads version; unchanged,
// proven, not on the critical path).
// ---------------------------------------------------------------------------
__device__ __forceinline__ void stage_tile(
    const __hip_bfloat16* __restrict__ Ap, const __hip_bfloat16* __restrict__ Bp,
    int LDK, int ktv, int m0, int n0, int tid, int wave,
    __hip_bfloat16* sA, __hip_bfloat16* sB) {
#pragma unroll
  for (int c = 0; c < 4; ++c) {
    const int q = c * 256 + tid;
    const int row = q >> 3, slot = q & 7;
    const int scol = ((slot ^ (row & 7)) << 3);
    gload_lds16(&Ap[(m0 + row) * LDK + ktv + scol], &sA[(c * 256 + wave * 64) << 3]);
    gload_lds16(&Bp[(n0 + row) * LDK + ktv + scol], &sB[(c * 256 + wave * 64) << 3]);
  }
}

__global__ __launch_bounds__(NT)
void psi_mfma(const __hip_bfloat16* __restrict__ wb,
              const __hip_bfloat16* __restrict__ DT,
              __hip_bfloat16* __restrict__ PT) {
  const int m0 = blockIdx.x * 128, n0 = blockIdx.y * 128;

  __shared__ __hip_bfloat16 sA[2][128 * 64];
  __shared__ __hip_bfloat16 sB[2][128 * 64];

  const int tid = threadIdx.x;
  const int lane = tid & 63, wave = tid >> 6;
  const int wr = wave & 1, wc = wave >> 1;
  const int r15 = lane & 15, khi = lane >> 4;

  f32x4 acc[4][4] = {};
  bf16x8 af[4][2], bf[4][2];

  stage_tile(wb, DT, 512, 0, m0, n0, tid, wave, sA[0], sB[0]);
  __syncthreads();
  int cur = 0;
  for (int t = 0; t < 8; ++t) {
    if (t + 1 < 8)
      stage_tile(wb, DT, 512, (t + 1) << 6, m0, n0, tid, wave, sA[cur ^ 1], sB[cur ^ 1]);
    load_frags(sA[cur], sB[cur], wr, wc, r15, khi, af, bf);
    do_mfma(af, bf, acc);
    if (t + 1 < 8) { __syncthreads(); cur ^= 1; }
  }

#pragma unroll
  for (int n = 0; n < 4; ++n) {
    const int s = n0 + wc * 64 + n * 16 + r15;
    if (s >= 286) continue;
    int off, d;
    decode_s(s, off, d);
    const int rel = s - off;
    const int u = rel / d, v = rel - u * d;
    const float scale = 1.0f / (256.0f * sqrtf((float)d));
    __hip_bfloat16* Pl = PT + off * 16384;
    const int Kd = 128 * d;
#pragma unroll
    for (int m = 0; m < 4; ++m)
#pragma unroll
      for (int j = 0; j < 4; ++j) {
        const int row = m0 + wr * 64 + m * 16 + khi * 4 + j;
        const int x = row >> 7, y = row & 127;
        Pl[(y * d + v) * Kd + (x * d + u)] = __float2bfloat16(acc[m][n][j] * scale);
      }
  }
}

// ---------------------------------------------------------------------------
// Kernel 2: main GEMM, counted-vmcnt pipeline.
// Per K-step: {issue 8 gload_lds for NEXT step} -> s_waitcnt vmcnt(8) (keeps
// the 8 just-issued in flight; waits only for CURRENT buffer) -> raw
// s_barrier -> ds_read frags + MFMA (setprio 1) -> raw s_barrier -> swap.
// No vmcnt(0) drain in the main loop (T4); last iter drains.
// ---------------------------------------------------------------------------
template<int D, int OFF>
__device__ __forceinline__ void tile_body(
    const __hip_bfloat16* __restrict__ Aall,
    const __hip_bfloat16* __restrict__ PTall,
    float* __restrict__ out, int bx,
    __hip_bfloat16* s0A, __hip_bfloat16* s0B,
    __hip_bfloat16* s1A, __hip_bfloat16* s1B) {
  const int tid = threadIdx.x;
  const int lane = tid & 63, wave = tid >> 6;
  const int wr = wave & 1, wc = wave >> 1;
  const int r15 = lane & 15, khi = lane >> 4;

  constexpr int Kn = 128 * D;
  constexpr int nk = 2 * D;
  const int bm = bx % (4 * D);       // bm fastest: consecutive blocks share BT
  const int bn = bx / (4 * D);
  const __hip_bfloat16* A  = Aall  + 65536 * OFF;
  const __hip_bfloat16* BT = PTall + 16384 * OFF;
  const int m0 = bm * 128, n0 = bn * 128;

  // staging geometry (4 x 2 gload_lds per thread = 8 vmem ops per stage)
  const int q0 = tid;  // q = c*256 + tid
  f32x4 acc[4][4] = {};
  bf16x8 af[4][2], bf[4][2];

  __hip_bfloat16 *curA = s0A, *curB = s0B, *nxtA = s1A, *nxtB = s1B;

  // prologue: stage K-step 0 into buf0 (8 outstanding vmem ops/wave)
#pragma unroll
  for (int c = 0; c < 4; ++c) {
    const int q = c * 256 + q0;
    const int row = q >> 3, slot = q & 7;
    const int scol = ((slot ^ (row & 7)) << 3);
    gload_lds16(&A[(m0 + row) * Kn + scol], &curA[(c * 256 + wave * 64) << 3]);
    gload_lds16(&BT[(n0 + row) * Kn + scol], &curB[(c * 256 + wave * 64) << 3]);
  }

  for (int t = 0; t < nk; ++t) {
    if (t + 1 < nk) {
      const int kt = (t + 1) << 6;
#pragma unroll
      for (int c = 0; c < 4; ++c) {
        const int q = c * 256 + q0;
        const int row = q >> 3, slot = q & 7;
        const int scol = ((slot ^ (row & 7)) << 3);
        gload_lds16(&A[(m0 + row) * Kn + kt + scol], &nxtA[(c * 256 + wave * 64) << 3]);
        gload_lds16(&BT[(n0 + row) * Kn + kt + scol], &nxtB[(c * 256 + wave * 64) << 3]);
      }
      // wait for CURRENT buffer only; the 8 just-issued stay in flight
      asm volatile("s_waitcnt vmcnt(8)" ::: "memory");
    } else {
      asm volatile("s_waitcnt vmcnt(0)" ::: "memory");
    }
    __builtin_amdgcn_s_barrier();          // raw: no compiler waitcnt drain
    asm volatile("" ::: "memory");

    load_frags(curA, curB, wr, wc, r15, khi, af, bf);
    __builtin_amdgcn_s_setprio(1);
    do_mfma(af, bf, acc);
    __builtin_amdgcn_s_setprio(0);

    asm volatile("" ::: "memory");
    __builtin_amdgcn_s_barrier();          // all reads of cur done before overwrite
    __hip_bfloat16* tA = curA; curA = nxtA; nxtA = tA;
    __hip_bfloat16* tB = curB; curB = nxtB; nxtB = tB;
  }

  // Direct-scatter epilogue (R9-proven), compile-time D divisions.
  int yo4[4], v4[4];
#pragma unroll
  for (int n = 0; n < 4; ++n) {
    const int col = n0 + wc * 64 + n * 16 + r15;
    yo4[n] = col / D;
    v4[n] = col - yo4[n] * D;
  }
#pragma unroll
  for (int m = 0; m < 4; ++m)
#pragma unroll
    for (int j = 0; j < 4; ++j) {
      const int row = m0 + wr * 64 + m * 16 + khi * 4 + j;
      const int bb = row / D, i = row - bb * D;
      float* orow = out + (size_t)bb * 36608 + OFF + i;
#pragma unroll
      for (int n = 0; n < 4; ++n)
        orow[yo4[n] * 286 + v4[n] * D] = acc[m][n][j];
    }
}

__global__ __launch_bounds__(NT)
void main_gemm(const __hip_bfloat16* __restrict__ Aall,
               const __hip_bfloat16* __restrict__ PTall,
               float* __restrict__ out) {
  __shared__ __hip_bfloat16 sA[2][128 * 64];
  __shared__ __hip_bfloat16 sB[2][128 * 64];
  const int bx = blockIdx.x;
  if (bx < 484)       tile_body<11, 165>(Aall, PTall, out, bx,        sA[0], sB[0], sA[1], sB[1]);
  else if (bx < 808)  tile_body<9, 84>(Aall, PTall, out, bx - 484,   sA[0], sB[0], sA[1], sB[1]);
  else if (bx < 1004) tile_body<7, 35>(Aall, PTall, out, bx - 808,   sA[0], sB[0], sA[1], sB[1]);
  else if (bx < 1104) tile_body<5, 10>(Aall, PTall, out, bx - 1004,  sA[0], sB[0], sA[1], sB[1]);
  else if (bx < 1140) tile_body<3, 1>(Aall, PTall, out, bx - 1104,   sA[0], sB[0], sA[1], sB[1]);
  else                tile_body<1, 0>(Aall, PTall, out, bx - 1140,   sA[0], sB[0], sA[1], sB[1]);
}

// ---------------------------------------------------------------------------
extern "C" void kernel_launch(void* const* d_in, const int* in_sizes, int n_in,
                              void* d_out, int out_size, void* d_ws, size_t ws_size,
                              hipStream_t stream) {
  const float* x  = (const float*)d_in[0];  // (512,128,286)
  const float* w  = (const float*)d_in[1];  // (128,128,512)
  const float* Dm = (const float*)d_in[2];  // (512,286)
  float* out = (float*)d_out;               // (512,128,286)

  // Workspace (bf16 elems): PT 16384*286 ; A 65536*286 ; wb 16384*512 ;
  // DT 384*512.
  __hip_bfloat16* PT = (__hip_bfloat16*)d_ws;
  __hip_bfloat16* A  = PT + 16384 * 286;
  __hip_bfloat16* wb = A + 65536 * 286;
  __hip_bfloat16* DT = wb + 16384 * 512;

  prep_all<<<dim3(7936), dim3(NT), 0, stream>>>(w, Dm, x, wb, DT, A);
  psi_mfma<<<dim3(128, 3), dim3(NT), 0, stream>>>(wb, DT, PT);
  main_gemm<<<dim3(1144), dim3(NT), 0, stream>>>(A, PT, out);
}

// Round 13
// 162.480 us; speedup vs baseline: 1.1042x; 1.0105x over previous
//
#include <hip/hip_runtime.h>
#include <hip/hip_bf16.h>

// SO3Conv restructured:
//   PT_l[(yo,v)][(x,u)] = psi_l scaled, bf16   (psi = D.w/sqrt(512))
//   A_l[(b,i)][(x,u)]   = permuted x, bf16
//   Y_l[(b,i)][(yo,v)]  = A_l . PT_l^T  via mfma_f32_16x16x32_bf16
// l=0..5, d=2l+1, off_l = {0,1,10,35,84,165}.
// main_gemm: 1144 128x128 tiles, template-D bodies, ping-pong LDS + counted
// vmcnt(8) + raw s_barrier (R12), NEW: LDS-bounce coalesced epilogue (v2) —
// acc -> sE[128][129] f32 (aliases staging LDS) -> out-order contiguous
// stores (d^2-blocks contiguous; ~7x fewer L2 write transactions).

#define NT 256
typedef __bf16 bf16x8 __attribute__((ext_vector_type(8)));
typedef float f32x4 __attribute__((ext_vector_type(4)));
typedef unsigned int u32;

__device__ __forceinline__ void gload_lds16(const void* g, void* l) {
  __builtin_amdgcn_global_load_lds(
      (const __attribute__((address_space(1))) u32*)g,
      (__attribute__((address_space(3))) u32*)l, 16, 0, 0);
}

__device__ __forceinline__ void decode_s(int s, int& off, int& d) {
  if (s >= 165)      { off = 165; d = 11; }
  else if (s >= 84)  { off = 84;  d = 9; }
  else if (s >= 35)  { off = 35;  d = 7; }
  else if (s >= 10)  { off = 10;  d = 5; }
  else if (s >= 1)   { off = 1;   d = 3; }
  else               { off = 0;   d = 1; }
}

// ---------------------------------------------------------------------------
// Kernel 0: prep_all (7936 blocks).
//   [0,4096):    wb = bf16(w), 8 elems/thread.
//   [4096,4864): DT[s][g] = bf16(D[g][s]), padded to 384 rows.
//   [4864,7936): build_A — per (b,l) LDS transpose, compile-time D/OFF.
// ---------------------------------------------------------------------------
template<int D, int OFF>
__device__ __forceinline__ void build_one(const float* __restrict__ X,
                                          __hip_bfloat16* __restrict__ A,
                                          int b, __hip_bfloat16* sm) {
  const float* src = X + (size_t)b * (128 * 286) + OFF;
  for (int e = threadIdx.x; e < 128 * D * D; e += NT) {
    const int x = e / (D * D), r = e - x * (D * D);
    sm[e] = __float2bfloat16(src[x * 286 + r]);
  }
  __syncthreads();
  __hip_bfloat16* dst = A + (size_t)65536 * OFF + (size_t)b * (D * 128 * D);
  for (int o = threadIdx.x; o < D * 128 * D; o += NT) {
    const int i = o / (128 * D);
    const int rem = o - i * (128 * D);
    const int x = rem / D, u = rem - x * D;
    dst[o] = sm[x * D * D + u * D + i];
  }
}

__global__ __launch_bounds__(NT)
void prep_all(const float* __restrict__ w, const float* __restrict__ Dm,
              const float* __restrict__ X,
              __hip_bfloat16* __restrict__ wb, __hip_bfloat16* __restrict__ DT,
              __hip_bfloat16* __restrict__ A) {
  __shared__ __hip_bfloat16 sm[128 * 121];
  const int bx = blockIdx.x;
  if (bx < 4096) {
    const int t = bx * NT + threadIdx.x;
    const float4 a = reinterpret_cast<const float4*>(w)[t * 2];
    const float4 b = reinterpret_cast<const float4*>(w)[t * 2 + 1];
    __hip_bfloat16 v[8];
    v[0] = __float2bfloat16(a.x); v[1] = __float2bfloat16(a.y);
    v[2] = __float2bfloat16(a.z); v[3] = __float2bfloat16(a.w);
    v[4] = __float2bfloat16(b.x); v[5] = __float2bfloat16(b.y);
    v[6] = __float2bfloat16(b.z); v[7] = __float2bfloat16(b.w);
    *reinterpret_cast<bf16x8*>(&wb[t * 8]) = *reinterpret_cast<bf16x8*>(v);
  } else if (bx < 4864) {
    const int e = (bx - 4096) * NT + threadIdx.x;  // 196,608 = 384*512
    const int s = e >> 9, g = e & 511;
    DT[e] = (s < 286) ? __float2bfloat16(Dm[g * 286 + s]) : __float2bfloat16(0.0f);
  } else {
    const int b2 = bx - 4864;
    if (b2 < 512)       build_one<11, 165>(X, A, b2, sm);
    else if (b2 < 1024) build_one<9, 84>(X, A, b2 - 512, sm);
    else if (b2 < 1536) build_one<7, 35>(X, A, b2 - 1024, sm);
    else if (b2 < 2048) build_one<5, 10>(X, A, b2 - 1536, sm);
    else if (b2 < 2560) build_one<3, 1>(X, A, b2 - 2048, sm);
    else                build_one<1, 0>(X, A, b2 - 2560, sm);
  }
}

// ---------------------------------------------------------------------------
// Shared helpers (proven R7 structure).
// ---------------------------------------------------------------------------
__device__ __forceinline__ void load_frags(
    const __hip_bfloat16* sA, const __hip_bfloat16* sB,
    int wr, int wc, int r15, int khi, bf16x8 (&af)[4][2], bf16x8 (&bf)[4][2]) {
#pragma unroll
  for (int m = 0; m < 4; ++m)
#pragma unroll
    for (int kk = 0; kk < 2; ++kk) {
      const int row = wr * 64 + m * 16 + r15;
      const int slot = (kk * 4 + khi) ^ (row & 7);
      af[m][kk] = *reinterpret_cast<const bf16x8*>(&sA[row * 64 + slot * 8]);
    }
#pragma unroll
  for (int n = 0; n < 4; ++n)
#pragma unroll
    for (int kk = 0; kk < 2; ++kk) {
      const int row = wc * 64 + n * 16 + r15;
      const int slot = (kk * 4 + khi) ^ (row & 7);
      bf[n][kk] = *reinterpret_cast<const bf16x8*>(&sB[row * 64 + slot * 8]);
    }
}

__device__ __forceinline__ void do_mfma(
    const bf16x8 (&af)[4][2], const bf16x8 (&bf)[4][2], f32x4 (&acc)[4][4]) {
#pragma unroll
  for (int kk = 0; kk < 2; ++kk)
#pragma unroll
    for (int m = 0; m < 4; ++m)
#pragma unroll
      for (int n = 0; n < 4; ++n)
        acc[m][n] = __builtin_amdgcn_mfma_f32_16x16x32_bf16(
            af[m][kk], bf[n][kk], acc[m][n], 0, 0, 0);
}

// ---------------------------------------------------------------------------
// Kernel 1: psi MFMA GEMM (double-buffered; unchanged, proven).
// ---------------------------------------------------------------------------
__device__ __forceinline__ void stage_tile(
    const __hip_bfloat16* __restrict__ Ap, const __hip_bfloat16* __restrict__ Bp,
    int LDK, int ktv, int m0, int n0, int tid, int wave,
    __hip_bfloat16* sA, __hip_bfloat16* sB) {
#pragma unroll
  for (int c = 0; c < 4; ++c) {
    const int q = c * 256 + tid;
    const int row = q >> 3, slot = q & 7;
    const int scol = ((slot ^ (row & 7)) << 3);
    gload_lds16(&Ap[(m0 + row) * LDK + ktv + scol], &sA[(c * 256 + wave * 64) << 3]);
    gload_lds16(&Bp[(n0 + row) * LDK + ktv + scol], &sB[(c * 256 + wave * 64) << 3]);
  }
}

__global__ __launch_bounds__(NT)
void psi_mfma(const __hip_bfloat16* __restrict__ wb,
              const __hip_bfloat16* __restrict__ DT,
              __hip_bfloat16* __restrict__ PT) {
  const int m0 = blockIdx.x * 128, n0 = blockIdx.y * 128;

  __shared__ __hip_bfloat16 sA[2][128 * 64];
  __shared__ __hip_bfloat16 sB[2][128 * 64];

  const int tid = threadIdx.x;
  const int lane = tid & 63, wave = tid >> 6;
  const int wr = wave & 1, wc = wave >> 1;
  const int r15 = lane & 15, khi = lane >> 4;

  f32x4 acc[4][4] = {};
  bf16x8 af[4][2], bf[4][2];

  stage_tile(wb, DT, 512, 0, m0, n0, tid, wave, sA[0], sB[0]);
  __syncthreads();
  int cur = 0;
  for (int t = 0; t < 8; ++t) {
    if (t + 1 < 8)
      stage_tile(wb, DT, 512, (t + 1) << 6, m0, n0, tid, wave, sA[cur ^ 1], sB[cur ^ 1]);
    load_frags(sA[cur], sB[cur], wr, wc, r15, khi, af, bf);
    do_mfma(af, bf, acc);
    if (t + 1 < 8) { __syncthreads(); cur ^= 1; }
  }

#pragma unroll
  for (int n = 0; n < 4; ++n) {
    const int s = n0 + wc * 64 + n * 16 + r15;
    if (s >= 286) continue;
    int off, d;
    decode_s(s, off, d);
    const int rel = s - off;
    const int u = rel / d, v = rel - u * d;
    const float scale = 1.0f / (256.0f * sqrtf((float)d));
    __hip_bfloat16* Pl = PT + off * 16384;
    const int Kd = 128 * d;
#pragma unroll
    for (int m = 0; m < 4; ++m)
#pragma unroll
      for (int j = 0; j < 4; ++j) {
        const int row = m0 + wr * 64 + m * 16 + khi * 4 + j;
        const int x = row >> 7, y = row & 127;
        Pl[(y * d + v) * Kd + (x * d + u)] = __float2bfloat16(acc[m][n][j] * scale);
      }
  }
}

// ---------------------------------------------------------------------------
// Kernel 2: main GEMM — R12 K-loop (counted vmcnt(8), raw barriers, setprio)
// + v2 coalesced epilogue (D>=3): acc -> sE[128][129] f32 -> out-order sweep.
// ---------------------------------------------------------------------------
template<int D, int OFF>
__device__ __forceinline__ void tile_body(
    const __hip_bfloat16* __restrict__ Aall,
    const __hip_bfloat16* __restrict__ PTall,
    float* __restrict__ out, int bx,
    __hip_bfloat16* s0A, __hip_bfloat16* s0B,
    __hip_bfloat16* s1A, __hip_bfloat16* s1B, float* sE) {
  const int tid = threadIdx.x;
  const int lane = tid & 63, wave = tid >> 6;
  const int wr = wave & 1, wc = wave >> 1;
  const int r15 = lane & 15, khi = lane >> 4;

  constexpr int Kn = 128 * D;
  constexpr int nk = 2 * D;
  const int bm = bx % (4 * D);
  const int bn = bx / (4 * D);
  const __hip_bfloat16* A  = Aall  + 65536 * OFF;
  const __hip_bfloat16* BT = PTall + 16384 * OFF;
  const int m0 = bm * 128, n0 = bn * 128;

  const int q0 = tid;
  f32x4 acc[4][4] = {};
  bf16x8 af[4][2], bf[4][2];

  __hip_bfloat16 *curA = s0A, *curB = s0B, *nxtA = s1A, *nxtB = s1B;

#pragma unroll
  for (int c = 0; c < 4; ++c) {
    const int q = c * 256 + q0;
    const int row = q >> 3, slot = q & 7;
    const int scol = ((slot ^ (row & 7)) << 3);
    gload_lds16(&A[(m0 + row) * Kn + scol], &curA[(c * 256 + wave * 64) << 3]);
    gload_lds16(&BT[(n0 + row) * Kn + scol], &curB[(c * 256 + wave * 64) << 3]);
  }

  for (int t = 0; t < nk; ++t) {
    if (t + 1 < nk) {
      const int kt = (t + 1) << 6;
#pragma unroll
      for (int c = 0; c < 4; ++c) {
        const int q = c * 256 + q0;
        const int row = q >> 3, slot = q & 7;
        const int scol = ((slot ^ (row & 7)) << 3);
        gload_lds16(&A[(m0 + row) * Kn + kt + scol], &nxtA[(c * 256 + wave * 64) << 3]);
        gload_lds16(&BT[(n0 + row) * Kn + kt + scol], &nxtB[(c * 256 + wave * 64) << 3]);
      }
      asm volatile("s_waitcnt vmcnt(8)" ::: "memory");
    } else {
      asm volatile("s_waitcnt vmcnt(0)" ::: "memory");
    }
    __builtin_amdgcn_s_barrier();
    asm volatile("" ::: "memory");

    load_frags(curA, curB, wr, wc, r15, khi, af, bf);
    __builtin_amdgcn_s_setprio(1);
    do_mfma(af, bf, acc);
    __builtin_amdgcn_s_setprio(0);

    asm volatile("" ::: "memory");
    __builtin_amdgcn_s_barrier();
    __hip_bfloat16* tA = curA; curA = nxtA; nxtA = tA;
    __hip_bfloat16* tB = curB; curB = nxtB; nxtB = tB;
  }

  if constexpr (D == 1) {
    // tiny degree: direct scatter (out cols = yo, contiguous-ish anyway)
#pragma unroll
    for (int m = 0; m < 4; ++m)
#pragma unroll
      for (int j = 0; j < 4; ++j) {
        const int row = m0 + wr * 64 + m * 16 + khi * 4 + j;   // = b
        float* orow = out + (size_t)row * 36608 + OFF;
#pragma unroll
        for (int n = 0; n < 4; ++n) {
          const int col = n0 + wc * 64 + n * 16 + r15;          // = yo
          orow[col * 286] = acc[m][n][j];
        }
      }
  } else {
    // v2: acc -> sE (f32, pad 129) -> out-order coalesced sweep
    __syncthreads();   // all staging-LDS use complete before aliasing as sE
#pragma unroll
    for (int m = 0; m < 4; ++m)
#pragma unroll
      for (int n = 0; n < 4; ++n)
#pragma unroll
        for (int j = 0; j < 4; ++j) {
          const int row = wr * 64 + m * 16 + khi * 4 + j;
          const int col = wc * 64 + n * 16 + r15;
          sE[row * 129 + col] = acc[m][n][j];
        }
    __syncthreads();

    constexpr int DD = D * D;
    constexpr int NBB = (128 + D - 1) / D + 1;
    constexpr int TOT = NBB * NBB * DD;
    const int b0 = m0 / D;
    const int yo0 = n0 / D;
    for (int e = tid; e < TOT; e += NT) {
      const int t2 = e / DD;
      const int s = e - t2 * DD;
      const int yyi = t2 % NBB;
      const int bbi = t2 / NBB;
      const int i = s % D, v = s / D;           // i fastest -> contiguous out
      const int b = b0 + bbi, yo = yo0 + yyi;
      const int row = b * D + i - m0;
      const int col = yo * D + v - n0;
      if ((unsigned)row < 128u && (unsigned)col < 128u && b < 512 && yo < 128)
        out[(size_t)b * 36608 + yo * 286 + OFF + v * D + i] = sE[row * 129 + col];
    }
  }
}

__global__ __launch_bounds__(NT)
void main_gemm(const __hip_bfloat16* __restrict__ Aall,
               const __hip_bfloat16* __restrict__ PTall,
               float* __restrict__ out) {
  __shared__ __align__(16) unsigned char smem[66560];  // 4x16K staging | 66K sE
  __hip_bfloat16* s0A = (__hip_bfloat16*)smem;
  __hip_bfloat16* s0B = (__hip_bfloat16*)(smem + 16384);
  __hip_bfloat16* s1A = (__hip_bfloat16*)(smem + 32768);
  __hip_bfloat16* s1B = (__hip_bfloat16*)(smem + 49152);
  float* sE = (float*)smem;
  const int bx = blockIdx.x;
  if (bx < 484)       tile_body<11, 165>(Aall, PTall, out, bx,       s0A, s0B, s1A, s1B, sE);
  else if (bx < 808)  tile_body<9, 84>(Aall, PTall, out, bx - 484,  s0A, s0B, s1A, s1B, sE);
  else if (bx < 1004) tile_body<7, 35>(Aall, PTall, out, bx - 808,  s0A, s0B, s1A, s1B, sE);
  else if (bx < 1104) tile_body<5, 10>(Aall, PTall, out, bx - 1004, s0A, s0B, s1A, s1B, sE);
  else if (bx < 1140) tile_body<3, 1>(Aall, PTall, out, bx - 1104,  s0A, s0B, s1A, s1B, sE);
  else                tile_body<1, 0>(Aall, PTall, out, bx - 1140,  s0A, s0B, s1A, s1B, sE);
}

// ---------------------------------------------------------------------------
extern "C" void kernel_launch(void* const* d_in, const int* in_sizes, int n_in,
                              void* d_out, int out_size, void* d_ws, size_t ws_size,
                              hipStream_t stream) {
  const float* x  = (const float*)d_in[0];  // (512,128,286)
  const float* w  = (const float*)d_in[1];  // (128,128,512)
  const float* Dm = (const float*)d_in[2];  // (512,286)
  float* out = (float*)d_out;               // (512,128,286)

  // Workspace (bf16 elems): PT 16384*286 ; A 65536*286 ; wb 16384*512 ;
  // DT 384*512.
  __hip_bfloat16* PT = (__hip_bfloat16*)d_ws;
  __hip_bfloat16* A  = PT + 16384 * 286;
  __hip_bfloat16* wb = A + 65536 * 286;
  __hip_bfloat16* DT = wb + 16384 * 512;

  prep_all<<<dim3(7936), dim3(NT), 0, stream>>>(w, Dm, x, wb, DT, A);
  psi_mfma<<<dim3(128, 3), dim3(NT), 0, stream>>>(wb, DT, PT);
  main_gemm<<<dim3(1144), dim3(NT), 0, stream>>>(A, PT, out);
}